// Round 3
// baseline (580.800 us; speedup 1.0000x reference)
//
#include <hip/hip_runtime.h>
#include <hip/hip_bf16.h>

// Problem constants (from reference setup_inputs):
//   B=8, T=4096, x0:[8,1024,4096] f32, x1:[8,768,4096] f32
//   BC=256, RC=64, NB0=4, NB1=3, TB=7, EPS=1e-5, LOWEST=0
#define B_SZ 8
#define T_SZ 4096
#define BC 256
#define RC 64
#define NB0 4
#define NB1 3
#define TB 7
#define ROWS0 (B_SZ * 1024)            // 8192 rows in x0
#define ROWS1 (B_SZ * 768)             // 6144 rows in x1
#define ROWS_TOTAL (ROWS0 + ROWS1)     // 14336
#define X0_ELEMS (33554432ull)         // 8*1024*4096

// native vector type usable with __builtin_nontemporal_store
typedef float vfloat4 __attribute__((ext_vector_type(4)));

// ---------------------------------------------------------------------------
// Kernel 1: per-row mean over time -> rowsum[row]. One wave per row of 4096
// floats (1024 float4, 16/lane). No atomics, no init required.
// ---------------------------------------------------------------------------
__global__ __launch_bounds__(256) void rowsum_kernel(const float* __restrict__ x0,
                                                     const float* __restrict__ x1,
                                                     float* __restrict__ rowsum) {
    const int gtid = blockIdx.x * blockDim.x + threadIdx.x;
    const int row  = gtid >> 6;
    const int lane = threadIdx.x & 63;

    const vfloat4* src = (row < ROWS0)
        ? (const vfloat4*)(x0 + (size_t)row * T_SZ)
        : (const vfloat4*)(x1 + (size_t)(row - ROWS0) * T_SZ);

    float sum = 0.0f;
#pragma unroll
    for (int it = 0; it < 16; ++it) {
        vfloat4 v = src[it * 64 + lane];
        sum += (v.x + v.y) + (v.z + v.w);
    }
#pragma unroll
    for (int off = 32; off > 0; off >>= 1)
        sum += __shfl_down(sum, off, 64);

    if (lane == 0)
        rowsum[row] = sum * (1.0f / (float)T_SZ);
}

// ---------------------------------------------------------------------------
// Kernel 2: attention math. Grid = 8 blocks (one per batch b), 256 threads
// (thread = channel c).
//   gap[b,c] = sum of the 7 row-means mapping to (b,c)
//   h[b,r]   = relu((gap[b,:] @ W1[:,r] + b1[r]) * gamma[r]/sqrt(1+eps) + beta[r])
//   att[b,k,c] = softmax_k(h[b,:] @ Wh[k,:,c] + bh[k,c])
// ---------------------------------------------------------------------------
__global__ __launch_bounds__(256) void attn_kernel(const float* __restrict__ rowsum,
                                                   const float* __restrict__ W1,
                                                   const float* __restrict__ b1,
                                                   const float* __restrict__ gamma,
                                                   const float* __restrict__ beta,
                                                   const float* __restrict__ Wh,
                                                   const float* __restrict__ bh,
                                                   float* __restrict__ att) {
    __shared__ float s_gap[BC];
    __shared__ float s_part[256];
    __shared__ float s_h[RC];

    const int b   = blockIdx.x;
    const int tid = threadIdx.x;

    // gap for this (b, c=tid): 4 rows from x0, 3 rows from x1
    float g = 0.0f;
#pragma unroll
    for (int nb = 0; nb < NB0; ++nb)
        g += rowsum[b * 1024 + nb * BC + tid];
#pragma unroll
    for (int nb = 0; nb < NB1; ++nb)
        g += rowsum[ROWS0 + b * 768 + nb * BC + tid];
    s_gap[tid] = g;
    __syncthreads();

    // h: thread t = (r = t&63, quarter q = t>>6) computes partial dot over 64 c's
    {
        const int r = tid & 63;
        const int q = tid >> 6;
        float acc = 0.0f;
#pragma unroll
        for (int i = 0; i < 64; ++i) {
            const int c = q * 64 + i;
            acc = fmaf(s_gap[c], W1[c * RC + r], acc);
        }
        s_part[tid] = acc;
    }
    __syncthreads();
    if (tid < RC) {
        float acc = s_part[tid] + s_part[tid + 64] + s_part[tid + 128] + s_part[tid + 192];
        acc += b1[tid];
        acc = acc * (gamma[tid] * rsqrtf(1.0f + 1e-5f)) + beta[tid];
        s_h[tid] = fmaxf(acc, 0.0f);
    }
    __syncthreads();

    // scores + softmax over k; Wh reads coalesced across threads (contiguous c)
    float sc[TB];
    float mx = -1e30f;
#pragma unroll
    for (int k = 0; k < TB; ++k) {
        float acc = bh[k * BC + tid];
#pragma unroll
        for (int r = 0; r < RC; ++r)
            acc = fmaf(s_h[r], Wh[(k * RC + r) * BC + tid], acc);
        sc[k] = acc;
        mx = fmaxf(mx, acc);
    }
    float sum = 0.0f;
#pragma unroll
    for (int k = 0; k < TB; ++k) {
        sc[k] = __expf(sc[k] - mx);
        sum += sc[k];
    }
    const float inv = 1.0f / sum;
#pragma unroll
    for (int k = 0; k < TB; ++k)
        att[(b * TB + k) * BC + tid] = sc[k] * inv;
}

// ---------------------------------------------------------------------------
// Kernel 3: scale each row by its attention scalar. One block per row,
// 256 threads x 4 float4. Nontemporal stores keep x L3-resident (out is
// write-once, never read) so the x re-read stays an L3 hit.
// ---------------------------------------------------------------------------
__global__ __launch_bounds__(256) void scale_kernel(const float* __restrict__ x0,
                                                    const float* __restrict__ x1,
                                                    const float* __restrict__ att,
                                                    float* __restrict__ out) {
    const int row = blockIdx.x;
    const vfloat4* src;
    vfloat4* dst;
    float a;
    if (row < ROWS0) {
        const int b = row >> 10;
        const int ch = row & 1023;
        a = att[(b * TB + (ch >> 8)) * BC + (ch & 255)];
        src = (const vfloat4*)(x0 + (size_t)row * T_SZ);
        dst = (vfloat4*)(out + (size_t)row * T_SZ);
    } else {
        const int r = row - ROWS0;
        const int b = r / 768;
        const int ch = r - b * 768;
        a = att[(b * TB + NB0 + (ch >> 8)) * BC + (ch & 255)];
        src = (const vfloat4*)(x1 + (size_t)r * T_SZ);
        dst = (vfloat4*)(out + X0_ELEMS + (size_t)r * T_SZ);
    }
    const int tid = threadIdx.x;
#pragma unroll
    for (int it = 0; it < 4; ++it) {
        vfloat4 v = src[it * 256 + tid];
        v *= a;
        __builtin_nontemporal_store(v, &dst[it * 256 + tid]);
    }
}

extern "C" void kernel_launch(void* const* d_in, const int* in_sizes, int n_in,
                              void* d_out, int out_size, void* d_ws, size_t ws_size,
                              hipStream_t stream) {
    const float* x0    = (const float*)d_in[0];
    const float* x1    = (const float*)d_in[1];
    const float* W1    = (const float*)d_in[2];
    const float* b1    = (const float*)d_in[3];
    const float* gamma = (const float*)d_in[4];
    const float* beta  = (const float*)d_in[5];
    const float* Wh    = (const float*)d_in[6];
    const float* bh    = (const float*)d_in[7];
    float* out = (float*)d_out;

    float* rowsum = (float*)d_ws;           // 14336 floats
    float* att    = rowsum + ROWS_TOTAL;    // 14336 floats

    rowsum_kernel<<<ROWS_TOTAL / 4, 256, 0, stream>>>(x0, x1, rowsum);
    attn_kernel<<<B_SZ, 256, 0, stream>>>(rowsum, W1, b1, gamma, beta, Wh, bh, att);
    scale_kernel<<<ROWS_TOTAL, 256, 0, stream>>>(x0, x1, att, out);
}